// Round 1
// baseline (2154.393 us; speedup 1.0000x reference)
//
#include <hip/hip_runtime.h>
#include <math.h>

#define B_SZ 2
#define T_SEQ 2048
#define DM 1024
#define NH 16
#define DH 64
#define ROWS (B_SZ * T_SEQ)  // 4096
#define LN_EPS 1e-5f

// ---------------------------------------------------------------- LayerNorm
__global__ __launch_bounds__(256) void ln_kernel(const float* __restrict__ x,
                                                 const float* __restrict__ g,
                                                 const float* __restrict__ bta,
                                                 float* __restrict__ h) {
    int row = blockIdx.x;
    const float* xr = x + (size_t)row * DM;
    int tid = threadIdx.x;
    float4 v = ((const float4*)xr)[tid];  // 256 threads * 4 = 1024
    float s = v.x + v.y + v.z + v.w;
    float ss = v.x * v.x + v.y * v.y + v.z * v.z + v.w * v.w;
    for (int off = 1; off < 64; off <<= 1) {
        s += __shfl_xor(s, off);
        ss += __shfl_xor(ss, off);
    }
    __shared__ float sbuf[4], ssbuf[4];
    int wave = tid >> 6, lane = tid & 63;
    if (lane == 0) { sbuf[wave] = s; ssbuf[wave] = ss; }
    __syncthreads();
    s = sbuf[0] + sbuf[1] + sbuf[2] + sbuf[3];
    ss = ssbuf[0] + ssbuf[1] + ssbuf[2] + ssbuf[3];
    float mu = s * (1.0f / DM);
    float var = ss * (1.0f / DM) - mu * mu;
    float rs = rsqrtf(var + LN_EPS);
    float4 gg = ((const float4*)g)[tid];
    float4 bb = ((const float4*)bta)[tid];
    float4 o;
    o.x = (v.x - mu) * rs * gg.x + bb.x;
    o.y = (v.y - mu) * rs * gg.y + bb.y;
    o.z = (v.z - mu) * rs * gg.z + bb.z;
    o.w = (v.w - mu) * rs * gg.w + bb.w;
    ((float4*)(h + (size_t)row * DM))[tid] = o;
}

// ------------------------------------------------------- fp32 tiled GEMM
// C[M,N] = A[M,K] @ B[K,N] + bias[N] (+ resid[M,N] if RESID)
// BM=64, BN=64, BK=32; 256 threads; 4x4 micro-tile per thread.
template <bool RESID>
__global__ __launch_bounds__(256) void gemm_kernel(const float* __restrict__ A,
                                                   const float* __restrict__ B,
                                                   const float* __restrict__ bias,
                                                   const float* __restrict__ resid,
                                                   float* __restrict__ C,
                                                   int M, int N, int K) {
    __shared__ float As[64][36];  // pad 32->36: keeps float4 LDS stores 16B-aligned
    __shared__ float Bs[32][64];
    int tid = threadIdx.x;
    int tx = tid & 15, ty = tid >> 4;
    int row0 = blockIdx.y * 64, col0 = blockIdx.x * 64;
    float acc[4][4] = {};
    for (int k0 = 0; k0 < K; k0 += 32) {
        // A tile 64x32 = 512 float4
        for (int i = 0; i < 2; ++i) {
            int flat = tid + i * 256;
            int r = flat >> 3, c4 = flat & 7;
            float4 av = *(const float4*)(A + (size_t)(row0 + r) * K + k0 + c4 * 4);
            *(float4*)&As[r][c4 * 4] = av;
        }
        // B tile 32x64 = 512 float4
        for (int i = 0; i < 2; ++i) {
            int flat = tid + i * 256;
            int r = flat >> 4, c4 = flat & 15;
            float4 bv = *(const float4*)(B + (size_t)(k0 + r) * N + col0 + c4 * 4);
            *(float4*)&Bs[r][c4 * 4] = bv;
        }
        __syncthreads();
        for (int kk = 0; kk < 32; ++kk) {
            float a0 = As[ty * 4 + 0][kk];
            float a1 = As[ty * 4 + 1][kk];
            float a2 = As[ty * 4 + 2][kk];
            float a3 = As[ty * 4 + 3][kk];
            float4 b4 = *(const float4*)&Bs[kk][tx << 2];
            acc[0][0] += a0 * b4.x; acc[0][1] += a0 * b4.y; acc[0][2] += a0 * b4.z; acc[0][3] += a0 * b4.w;
            acc[1][0] += a1 * b4.x; acc[1][1] += a1 * b4.y; acc[1][2] += a1 * b4.z; acc[1][3] += a1 * b4.w;
            acc[2][0] += a2 * b4.x; acc[2][1] += a2 * b4.y; acc[2][2] += a2 * b4.z; acc[2][3] += a2 * b4.w;
            acc[3][0] += a3 * b4.x; acc[3][1] += a3 * b4.y; acc[3][2] += a3 * b4.z; acc[3][3] += a3 * b4.w;
        }
        __syncthreads();
    }
    int c = col0 + (tx << 2);
    float4 bb = *(const float4*)&bias[c];
    for (int i = 0; i < 4; ++i) {
        int r = row0 + ty * 4 + i;
        float4 vv;
        vv.x = acc[i][0] + bb.x;
        vv.y = acc[i][1] + bb.y;
        vv.z = acc[i][2] + bb.z;
        vv.w = acc[i][3] + bb.w;
        if (RESID) {
            float4 rr = *(const float4*)&resid[(size_t)r * N + c];
            vv.x += rr.x; vv.y += rr.y; vv.z += rr.z; vv.w += rr.w;
        }
        *(float4*)&C[(size_t)r * N + c] = vv;
    }
}

// ------------------------------------------------------------- Attention
// One block = 4 q-rows of one (b,h); one wave per q-row.
// Two-pass softmax: pass1 streams K tiles computing online (m,l); pass2
// recomputes scores, writes normalized attn exactly once (incl. causal
// zeros; d_out is poisoned), and accumulates PV into registers.
__global__ __launch_bounds__(256) void attn_kernel(const float* __restrict__ qkv,
                                                   float* __restrict__ attn,
                                                   float* __restrict__ ao) {
    int blk = blockIdx.x;
    int qt = blk % (T_SEQ / 4);
    int bh = blk / (T_SEQ / 4);
    int b = bh / NH, hh = bh % NH;
    int wave = threadIdx.x >> 6, lane = threadIdx.x & 63;
    int q = qt * 4 + wave;

    __shared__ float Ks[64][68];  // pad 64->68: float4-aligned rows, conflict-free dot reads
    __shared__ float Vs[64][64];
    __shared__ float q_sh[4][64];
    __shared__ float p_sh[4][64];

    const float scale = 0.125f;  // 1/sqrt(64)
    const float* Qbase = qkv + (size_t)(b * T_SEQ) * (3 * DM) + hh * DH;
    const float* Kbase = Qbase + DM;
    const float* Vbase = Qbase + 2 * DM;

    q_sh[wave][lane] = Qbase[(size_t)q * (3 * DM) + lane];

    int ktiles = (qt * 4) / 64 + 1;  // identical for all 4 waves in block

    // ---- Pass 1: online max & sum-of-exp
    float m = -1e30f, l = 0.0f;
    for (int kt = 0; kt < ktiles; ++kt) {
        __syncthreads();
        for (int i = 0; i < 4; ++i) {
            int flat = threadIdx.x + i * 256;  // 1024 float4 = 64x64 floats
            int r = flat >> 4, c4 = flat & 15;
            float4 kv = *(const float4*)(Kbase + (size_t)(kt * 64 + r) * (3 * DM) + c4 * 4);
            *(float4*)&Ks[r][c4 * 4] = kv;
        }
        __syncthreads();
        int k = kt * 64 + lane;
        if (k <= q) {
            float s = 0.0f;
            const float4* qv = (const float4*)&q_sh[wave][0];
            const float4* kv = (const float4*)&Ks[lane][0];
            for (int d4 = 0; d4 < 16; ++d4) {
                float4 qq = qv[d4], kk4 = kv[d4];
                s += qq.x * kk4.x + qq.y * kk4.y + qq.z * kk4.z + qq.w * kk4.w;
            }
            s *= scale;
            float mn = fmaxf(m, s);
            l = l * __expf(m - mn) + __expf(s - mn);
            m = mn;
        }
    }
    // wave-level (m,l) combine across 64 lanes
    for (int off = 1; off < 64; off <<= 1) {
        float mo = __shfl_xor(m, off);
        float lo = __shfl_xor(l, off);
        float mn = fmaxf(m, mo);
        l = l * __expf(m - mn) + lo * __expf(mo - mn);
        m = mn;
    }
    float inv_l = 1.0f / l;

    // ---- Pass 2: recompute scores, write attn, accumulate PV
    float acc = 0.0f;
    float* arow = attn + ((size_t)bh * T_SEQ + q) * T_SEQ;
    for (int kt = 0; kt < T_SEQ / 64; ++kt) {
        float p = 0.0f;
        if (kt < ktiles) {
            __syncthreads();
            for (int i = 0; i < 4; ++i) {
                int flat = threadIdx.x + i * 256;
                int r = flat >> 4, c4 = flat & 15;
                float4 kv = *(const float4*)(Kbase + (size_t)(kt * 64 + r) * (3 * DM) + c4 * 4);
                float4 vv = *(const float4*)(Vbase + (size_t)(kt * 64 + r) * (3 * DM) + c4 * 4);
                *(float4*)&Ks[r][c4 * 4] = kv;
                *(float4*)&Vs[r][c4 * 4] = vv;
            }
            __syncthreads();
            int k = kt * 64 + lane;
            if (k <= q) {
                float s = 0.0f;
                const float4* qv = (const float4*)&q_sh[wave][0];
                const float4* kv = (const float4*)&Ks[lane][0];
                for (int d4 = 0; d4 < 16; ++d4) {
                    float4 qq = qv[d4], kk4 = kv[d4];
                    s += qq.x * kk4.x + qq.y * kk4.y + qq.z * kk4.z + qq.w * kk4.w;
                }
                s *= scale;
                p = __expf(s - m) * inv_l;
            }
            p_sh[wave][lane] = p;  // same-wave RAW: compiler inserts lgkmcnt wait
            float pv = 0.0f;
            for (int kk = 0; kk < 64; ++kk) pv += p_sh[wave][kk] * Vs[kk][lane];
            acc += pv;
        }
        arow[kt * 64 + lane] = p;  // full row coverage incl. causal zeros
    }
    // out in [B,T,H*dh] layout for the out-proj GEMM
    ao[(size_t)(b * T_SEQ + q) * DM + hh * DH + lane] = acc;
}

// ---------------------------------------------------------------- launch
extern "C" void kernel_launch(void* const* d_in, const int* in_sizes, int n_in,
                              void* d_out, int out_size, void* d_ws, size_t ws_size,
                              hipStream_t stream) {
    const float* x     = (const float*)d_in[0];
    const float* ln_g  = (const float*)d_in[1];
    const float* ln_b  = (const float*)d_in[2];
    const float* qkv_w = (const float*)d_in[3];
    const float* qkv_b = (const float*)d_in[4];
    const float* out_w = (const float*)d_in[5];
    const float* out_b = (const float*)d_in[6];

    float* xout = (float*)d_out;                       // [4096,1024]
    float* attn = xout + (size_t)ROWS * DM;            // [2,16,2048,2048]

    float* h   = (float*)d_ws;                         // [4096,1024] (16 MB)
    float* qkv = h + (size_t)ROWS * DM;                // [4096,3072] (48 MB)
    float* ao  = h;  // h is dead after QKV GEMM; reuse as attention output

    ln_kernel<<<ROWS, 256, 0, stream>>>(x, ln_g, ln_b, h);

    gemm_kernel<false><<<dim3(3 * DM / 64, ROWS / 64), 256, 0, stream>>>(
        h, qkv_w, qkv_b, nullptr, qkv, ROWS, 3 * DM, DM);

    attn_kernel<<<B_SZ * NH * (T_SEQ / 4), 256, 0, stream>>>(qkv, attn, ao);

    gemm_kernel<true><<<dim3(DM / 64, ROWS / 64), 256, 0, stream>>>(
        ao, out_w, out_b, x, xout, ROWS, DM, DM);
}

// Round 2
// 1238.190 us; speedup vs baseline: 1.7400x; 1.7400x over previous
//
#include <hip/hip_runtime.h>
#include <math.h>

#define B_SZ 2
#define T_SEQ 2048
#define DM 1024
#define NH 16
#define DH 64
#define ROWS (B_SZ * T_SEQ)  // 4096
#define LN_EPS 1e-5f
#define LP 68  // LDS row stride (shorts): 136 B rows -> 8B-aligned, breaks pow2 bank alias

typedef __attribute__((ext_vector_type(8))) short short8;
typedef __attribute__((ext_vector_type(4))) float floatx4;

__device__ inline short f2bf(float f) {
    union { float f; unsigned u; } v; v.f = f;
    unsigned r = v.u + 0x7fffu + ((v.u >> 16) & 1u);  // RNE
    return (short)(r >> 16);
}
__device__ inline short8 ld8(const short* p) {  // two ds_read_b64 (rows are 8B-aligned)
    short4 a = *(const short4*)p;
    short4 b = *(const short4*)(p + 4);
    return short8{a.x, a.y, a.z, a.w, b.x, b.y, b.z, b.w};
}

// ---------------------------------------------------------------- LayerNorm
__global__ __launch_bounds__(256) void ln_kernel(const float* __restrict__ x,
                                                 const float* __restrict__ g,
                                                 const float* __restrict__ bta,
                                                 float* __restrict__ h) {
    int row = blockIdx.x;
    const float* xr = x + (size_t)row * DM;
    int tid = threadIdx.x;
    float4 v = ((const float4*)xr)[tid];
    float s = v.x + v.y + v.z + v.w;
    float ss = v.x * v.x + v.y * v.y + v.z * v.z + v.w * v.w;
    for (int off = 1; off < 64; off <<= 1) {
        s += __shfl_xor(s, off);
        ss += __shfl_xor(ss, off);
    }
    __shared__ float sbuf[4], ssbuf[4];
    int wave = tid >> 6, lane = tid & 63;
    if (lane == 0) { sbuf[wave] = s; ssbuf[wave] = ss; }
    __syncthreads();
    s = sbuf[0] + sbuf[1] + sbuf[2] + sbuf[3];
    ss = ssbuf[0] + ssbuf[1] + ssbuf[2] + ssbuf[3];
    float mu = s * (1.0f / DM);
    float var = ss * (1.0f / DM) - mu * mu;
    float rs = rsqrtf(var + LN_EPS);
    float4 gg = ((const float4*)g)[tid];
    float4 bb = ((const float4*)bta)[tid];
    float4 o;
    o.x = (v.x - mu) * rs * gg.x + bb.x;
    o.y = (v.y - mu) * rs * gg.y + bb.y;
    o.z = (v.z - mu) * rs * gg.z + bb.z;
    o.w = (v.w - mu) * rs * gg.w + bb.w;
    ((float4*)(h + (size_t)row * DM))[tid] = o;
}

// ------------------------------------------------------- fp32 tiled GEMM (unchanged)
template <bool RESID>
__global__ __launch_bounds__(256) void gemm_kernel(const float* __restrict__ A,
                                                   const float* __restrict__ B,
                                                   const float* __restrict__ bias,
                                                   const float* __restrict__ resid,
                                                   float* __restrict__ C,
                                                   int M, int N, int K) {
    __shared__ float As[64][36];
    __shared__ float Bs[32][64];
    int tid = threadIdx.x;
    int tx = tid & 15, ty = tid >> 4;
    int row0 = blockIdx.y * 64, col0 = blockIdx.x * 64;
    float acc[4][4] = {};
    for (int k0 = 0; k0 < K; k0 += 32) {
        for (int i = 0; i < 2; ++i) {
            int flat = tid + i * 256;
            int r = flat >> 3, c4 = flat & 7;
            float4 av = *(const float4*)(A + (size_t)(row0 + r) * K + k0 + c4 * 4);
            *(float4*)&As[r][c4 * 4] = av;
        }
        for (int i = 0; i < 2; ++i) {
            int flat = tid + i * 256;
            int r = flat >> 4, c4 = flat & 15;
            float4 bv = *(const float4*)(B + (size_t)(k0 + r) * N + col0 + c4 * 4);
            *(float4*)&Bs[r][c4 * 4] = bv;
        }
        __syncthreads();
        for (int kk = 0; kk < 32; ++kk) {
            float a0 = As[ty * 4 + 0][kk];
            float a1 = As[ty * 4 + 1][kk];
            float a2 = As[ty * 4 + 2][kk];
            float a3 = As[ty * 4 + 3][kk];
            float4 b4 = *(const float4*)&Bs[kk][tx << 2];
            acc[0][0] += a0 * b4.x; acc[0][1] += a0 * b4.y; acc[0][2] += a0 * b4.z; acc[0][3] += a0 * b4.w;
            acc[1][0] += a1 * b4.x; acc[1][1] += a1 * b4.y; acc[1][2] += a1 * b4.z; acc[1][3] += a1 * b4.w;
            acc[2][0] += a2 * b4.x; acc[2][1] += a2 * b4.y; acc[2][2] += a2 * b4.z; acc[2][3] += a2 * b4.w;
            acc[3][0] += a3 * b4.x; acc[3][1] += a3 * b4.y; acc[3][2] += a3 * b4.z; acc[3][3] += a3 * b4.w;
        }
        __syncthreads();
    }
    int c = col0 + (tx << 2);
    float4 bb = *(const float4*)&bias[c];
    for (int i = 0; i < 4; ++i) {
        int r = row0 + ty * 4 + i;
        float4 vv;
        vv.x = acc[i][0] + bb.x;
        vv.y = acc[i][1] + bb.y;
        vv.z = acc[i][2] + bb.z;
        vv.w = acc[i][3] + bb.w;
        if (RESID) {
            float4 rr = *(const float4*)&resid[(size_t)r * N + c];
            vv.x += rr.x; vv.y += rr.y; vv.z += rr.z; vv.w += rr.w;
        }
        *(float4*)&C[(size_t)r * N + c] = vv;
    }
}

// ------------------------------------------------------- MFMA flash attention
// Block = 64 q-rows of one (b,h); 4 waves x 16 rows. Two passes over k-tiles:
// pass1 accumulates softmax denominator l (no max subtraction: |s|<=~20, exp
// fits fp32 easily); pass2 recomputes S, writes attn=exp(s)/l once (zeros in
// the causal upper half), and accumulates O = P@V via MFMA with a per-wave
// LDS round-trip for P (C-layout -> A-layout).
__global__ __launch_bounds__(256) void attn_kernel(const float* __restrict__ qkv,
                                                   float* __restrict__ attn,
                                                   float* __restrict__ ao) {
    int blk = blockIdx.x;
    int qt = (T_SEQ / 64 - 1) - (blk & 31);  // big-q blocks first (tail balance)
    int bh = blk >> 5;
    int b = bh >> 4, hh = bh & 15;
    int q0 = qt * 64;
    int tid = threadIdx.x;
    int wave = tid >> 6, lane = tid & 63;
    int l15 = lane & 15, quad = lane >> 4;

    __shared__ short Qs[64 * LP];
    __shared__ short Ks[64 * LP];
    __shared__ short Vs[64 * LP];
    __shared__ short Ps[4][16 * LP];

    const float scale = 0.125f;  // 1/sqrt(64)
    const float* Qg = qkv + (size_t)(b * T_SEQ + q0) * (3 * DM) + hh * DH;
    const float* Kg = qkv + (size_t)(b * T_SEQ) * (3 * DM) + DM + hh * DH;
    const float* Vg = Kg + DM;

    // ---- stage Q (64x64) as bf16
    for (int i = 0; i < 4; ++i) {
        int flat = tid + i * 256;
        int r = flat >> 4, c4 = flat & 15;
        float4 v = *(const float4*)(Qg + (size_t)r * (3 * DM) + c4 * 4);
        short4 s4; s4.x = f2bf(v.x); s4.y = f2bf(v.y); s4.z = f2bf(v.z); s4.w = f2bf(v.w);
        *(short4*)&Qs[r * LP + c4 * 4] = s4;
    }
    __syncthreads();
    // Q A-fragments (fixed per wave): rows wave*16+l15, k-chunks d0*32+quad*8
    short8 qa[2];
    for (int d0 = 0; d0 < 2; ++d0)
        qa[d0] = ld8(&Qs[(wave * 16 + l15) * LP + d0 * 32 + quad * 8]);

    int ktiles = qt + 1;
    int qrow = q0 + wave * 16 + quad * 4;  // + reg

    // ---- pass 1: softmax denominators (4 rows per lane, replicated over l15)
    float lsum[4] = {0.f, 0.f, 0.f, 0.f};
    for (int kt = 0; kt < ktiles; ++kt) {
        __syncthreads();
        for (int i = 0; i < 4; ++i) {
            int flat = tid + i * 256;
            int r = flat >> 4, c4 = flat & 15;
            float4 v = *(const float4*)(Kg + (size_t)(kt * 64 + r) * (3 * DM) + c4 * 4);
            short4 s4; s4.x = f2bf(v.x); s4.y = f2bf(v.y); s4.z = f2bf(v.z); s4.w = f2bf(v.w);
            *(short4*)&Ks[r * LP + c4 * 4] = s4;
        }
        __syncthreads();
        floatx4 acc[4] = {};
        for (int n0 = 0; n0 < 4; ++n0)
            for (int d0 = 0; d0 < 2; ++d0) {
                short8 kb = ld8(&Ks[(n0 * 16 + l15) * LP + d0 * 32 + quad * 8]);
                acc[n0] = __builtin_amdgcn_mfma_f32_16x16x32_bf16(qa[d0], kb, acc[n0], 0, 0, 0);
            }
        int kbase = kt * 64 + l15;
        for (int r = 0; r < 4; ++r) {
            float s = 0.f;
            for (int n0 = 0; n0 < 4; ++n0) {
                float sc = acc[n0][r] * scale;
                s += (kbase + n0 * 16 <= qrow + r) ? __expf(sc) : 0.f;
            }
            s += __shfl_xor(s, 1); s += __shfl_xor(s, 2);
            s += __shfl_xor(s, 4); s += __shfl_xor(s, 8);
            lsum[r] += s;
        }
    }
    float invl[4];
    for (int r = 0; r < 4; ++r) invl[r] = 1.0f / lsum[r];

    // ---- pass 2: recompute S, write attn, accumulate O = P@V
    floatx4 oacc[4] = {};
    float* abase = attn + (size_t)bh * T_SEQ * T_SEQ;
    for (int kt = 0; kt < T_SEQ / 64; ++kt) {
        if (kt < ktiles) {
            __syncthreads();
            for (int i = 0; i < 4; ++i) {
                int flat = tid + i * 256;
                int r = flat >> 4, c4 = flat & 15;
                float4 kv = *(const float4*)(Kg + (size_t)(kt * 64 + r) * (3 * DM) + c4 * 4);
                float4 vv = *(const float4*)(Vg + (size_t)(kt * 64 + r) * (3 * DM) + c4 * 4);
                short4 a4; a4.x = f2bf(kv.x); a4.y = f2bf(kv.y); a4.z = f2bf(kv.z); a4.w = f2bf(kv.w);
                short4 b4; b4.x = f2bf(vv.x); b4.y = f2bf(vv.y); b4.z = f2bf(vv.z); b4.w = f2bf(vv.w);
                *(short4*)&Ks[r * LP + c4 * 4] = a4;
                *(short4*)&Vs[r * LP + c4 * 4] = b4;
            }
            __syncthreads();
            floatx4 acc[4] = {};
            for (int n0 = 0; n0 < 4; ++n0)
                for (int d0 = 0; d0 < 2; ++d0) {
                    short8 kb = ld8(&Ks[(n0 * 16 + l15) * LP + d0 * 32 + quad * 8]);
                    acc[n0] = __builtin_amdgcn_mfma_f32_16x16x32_bf16(qa[d0], kb, acc[n0], 0, 0, 0);
                }
            int kbase = kt * 64 + l15;
            for (int n0 = 0; n0 < 4; ++n0) {
                for (int r = 0; r < 4; ++r) {
                    float p = (kbase + n0 * 16 <= qrow + r)
                                  ? __expf(acc[n0][r] * scale) * invl[r] : 0.f;
                    abase[(size_t)(qrow + r) * T_SEQ + kbase + n0 * 16] = p;
                    Ps[wave][(quad * 4 + r) * LP + n0 * 16 + l15] = f2bf(p);
                }
            }
            __syncthreads();  // order Ps writes (cross-lane) before fragment reads
            for (int n0 = 0; n0 < 4; ++n0)
                for (int k0 = 0; k0 < 2; ++k0) {
                    short8 pf = ld8(&Ps[wave][l15 * LP + k0 * 32 + quad * 8]);
                    short bv[8];
#pragma unroll
                    for (int j = 0; j < 8; ++j)
                        bv[j] = Vs[(k0 * 32 + quad * 8 + j) * LP + n0 * 16 + l15];
                    short8 vf = short8{bv[0], bv[1], bv[2], bv[3], bv[4], bv[5], bv[6], bv[7]};
                    oacc[n0] = __builtin_amdgcn_mfma_f32_16x16x32_bf16(pf, vf, oacc[n0], 0, 0, 0);
                }
        } else {
            // causal upper half: attn = 0 (d_out is poisoned, must write)
            int kbase = kt * 64 + l15;
            for (int n0 = 0; n0 < 4; ++n0)
                for (int r = 0; r < 4; ++r)
                    abase[(size_t)(qrow + r) * T_SEQ + kbase + n0 * 16] = 0.f;
        }
    }
    // ---- epilogue: O to [B,T,H*dh] for the out-proj GEMM
    for (int n0 = 0; n0 < 4; ++n0)
        for (int r = 0; r < 4; ++r)
            ao[(size_t)(b * T_SEQ + qrow + r) * DM + hh * DH + n0 * 16 + l15] = oacc[n0][r];
}

// ---------------------------------------------------------------- launch
extern "C" void kernel_launch(void* const* d_in, const int* in_sizes, int n_in,
                              void* d_out, int out_size, void* d_ws, size_t ws_size,
                              hipStream_t stream) {
    const float* x     = (const float*)d_in[0];
    const float* ln_g  = (const float*)d_in[1];
    const float* ln_b  = (const float*)d_in[2];
    const float* qkv_w = (const float*)d_in[3];
    const float* qkv_b = (const float*)d_in[4];
    const float* out_w = (const float*)d_in[5];
    const float* out_b = (const float*)d_in[6];

    float* xout = (float*)d_out;
    float* attn = xout + (size_t)ROWS * DM;

    float* h   = (float*)d_ws;
    float* qkv = h + (size_t)ROWS * DM;
    float* ao  = h;  // h dead after QKV GEMM

    ln_kernel<<<ROWS, 256, 0, stream>>>(x, ln_g, ln_b, h);

    gemm_kernel<false><<<dim3(3 * DM / 64, ROWS / 64), 256, 0, stream>>>(
        h, qkv_w, qkv_b, nullptr, qkv, ROWS, 3 * DM, DM);

    attn_kernel<<<B_SZ * NH * (T_SEQ / 64), 256, 0, stream>>>(qkv, attn, ao);

    gemm_kernel<true><<<dim3(DM / 64, ROWS / 64), 256, 0, stream>>>(
        ao, out_w, out_b, x, xout, ROWS, DM, DM);
}

// Round 3
// 778.388 us; speedup vs baseline: 2.7678x; 1.5907x over previous
//
#include <hip/hip_runtime.h>
#include <math.h>

#define B_SZ 2
#define T_SEQ 2048
#define DM 1024
#define NH 16
#define DH 64
#define ROWS (B_SZ * T_SEQ)  // 4096
#define LN_EPS 1e-5f

typedef __attribute__((ext_vector_type(8))) short short8;
typedef __attribute__((ext_vector_type(4))) float floatx4;

__device__ __forceinline__ short f2bf(float f) {
    union { float f; unsigned u; } v; v.f = f;
    unsigned r = v.u + 0x7fffu + ((v.u >> 16) & 1u);  // RNE
    return (short)(r >> 16);
}
__device__ __forceinline__ short8 ld8(const short* p) {  // 8B-aligned pair of b64
    short4 a = *(const short4*)p;
    short4 b = *(const short4*)(p + 4);
    return short8{a.x, a.y, a.z, a.w, b.x, b.y, b.z, b.w};
}
// async 16B global->LDS (lds dest = wave-uniform base + lane*16)
__device__ __forceinline__ void gl2lds16(const void* g, void* l) {
    __builtin_amdgcn_global_load_lds(
        (const __attribute__((address_space(1))) unsigned int*)g,
        (__attribute__((address_space(3))) unsigned int*)l, 16, 0, 0);
}

// ---------------------------------------------------------------- LayerNorm (bf16 out)
__global__ __launch_bounds__(256) void ln_kernel(const float* __restrict__ x,
                                                 const float* __restrict__ g,
                                                 const float* __restrict__ bta,
                                                 short* __restrict__ h) {
    int row = blockIdx.x;
    const float* xr = x + (size_t)row * DM;
    int tid = threadIdx.x;
    float4 v = ((const float4*)xr)[tid];
    float s = v.x + v.y + v.z + v.w;
    float ss = v.x * v.x + v.y * v.y + v.z * v.z + v.w * v.w;
    for (int off = 1; off < 64; off <<= 1) {
        s += __shfl_xor(s, off);
        ss += __shfl_xor(ss, off);
    }
    __shared__ float sbuf[4], ssbuf[4];
    int wave = tid >> 6, lane = tid & 63;
    if (lane == 0) { sbuf[wave] = s; ssbuf[wave] = ss; }
    __syncthreads();
    s = sbuf[0] + sbuf[1] + sbuf[2] + sbuf[3];
    ss = ssbuf[0] + ssbuf[1] + ssbuf[2] + ssbuf[3];
    float mu = s * (1.0f / DM);
    float var = ss * (1.0f / DM) - mu * mu;
    float rs = rsqrtf(var + LN_EPS);
    float4 gg = ((const float4*)g)[tid];
    float4 bb = ((const float4*)bta)[tid];
    short4 o;
    o.x = f2bf((v.x - mu) * rs * gg.x + bb.x);
    o.y = f2bf((v.y - mu) * rs * gg.y + bb.y);
    o.z = f2bf((v.z - mu) * rs * gg.z + bb.z);
    o.w = f2bf((v.w - mu) * rs * gg.w + bb.w);
    *(short4*)&h[(size_t)row * DM + tid * 4] = o;
}

// ------------------------------------------- weight convert+transpose fp32[K,N]->bf16[N,K]
__global__ __launch_bounds__(256) void wt_kernel(const float* __restrict__ W,
                                                 short* __restrict__ Wt, int K, int N) {
    __shared__ float t[32][33];
    int tx = threadIdx.x & 31, ty = threadIdx.x >> 5;  // ty 0..7
    int k0 = blockIdx.y * 32, n0 = blockIdx.x * 32;
    for (int p = 0; p < 4; ++p)
        t[ty + 8 * p][tx] = W[(size_t)(k0 + ty + 8 * p) * N + n0 + tx];
    __syncthreads();
    for (int p = 0; p < 4; ++p)
        Wt[(size_t)(n0 + ty + 8 * p) * K + k0 + tx] = f2bf(t[tx][ty + 8 * p]);
}

// ------------------------------------------------------- bf16 MFMA GEMM (m97 structure)
// C[M,N] = A[M,K]bf16 @ Bt[N,K]bf16^T + bias; 128x128 tile, BK=32, 4 waves x 64x64.
template <bool RESID, bool BF16_OUT>
__global__ __launch_bounds__(256) void mfma_gemm(const short* __restrict__ A,
                                                 const short* __restrict__ Bt,
                                                 const float* __restrict__ bias,
                                                 const float* __restrict__ resid,
                                                 void* __restrict__ Cout,
                                                 int M, int N, int K) {
    __shared__ short As[128 * 32];
    __shared__ short Bs[128 * 32];
    int tid = threadIdx.x;
    int wave = tid >> 6, lane = tid & 63;
    int l15 = lane & 15, quad = lane >> 4;
    int wm = wave & 1, wn = wave >> 1;
    int row0 = blockIdx.y * 128, col0 = blockIdx.x * 128;

    floatx4 acc[4][4] = {};
    for (int k0 = 0; k0 < K; k0 += 32) {
        __syncthreads();
        for (int i = 0; i < 2; ++i) {
            int c = (wave * 2 + i) * 64 + lane;  // 16B chunk id, 512 per tile
            int row = c >> 2, kc = c & 3;
            gl2lds16(A + (size_t)(row0 + row) * K + k0 + kc * 8, &As[(wave * 2 + i) * 512]);
            gl2lds16(Bt + (size_t)(col0 + row) * K + k0 + kc * 8, &Bs[(wave * 2 + i) * 512]);
        }
        __syncthreads();  // drains vmcnt (global_load_lds) per barrier semantics
        short8 af[4], bfr[4];
        for (int m = 0; m < 4; ++m)
            af[m] = *(const short8*)&As[(wm * 64 + m * 16 + l15) * 32 + quad * 8];
        for (int n = 0; n < 4; ++n)
            bfr[n] = *(const short8*)&Bs[(wn * 64 + n * 16 + l15) * 32 + quad * 8];
        for (int m = 0; m < 4; ++m)
            for (int n = 0; n < 4; ++n)
                acc[m][n] = __builtin_amdgcn_mfma_f32_16x16x32_bf16(af[m], bfr[n], acc[m][n], 0, 0, 0);
    }
    float bias_v[4];
    for (int n = 0; n < 4; ++n) bias_v[n] = bias[col0 + wn * 64 + n * 16 + l15];
    for (int m = 0; m < 4; ++m)
        for (int r = 0; r < 4; ++r) {
            int rg = row0 + wm * 64 + m * 16 + quad * 4 + r;
            for (int n = 0; n < 4; ++n) {
                int cg = col0 + wn * 64 + n * 16 + l15;
                float v = acc[m][n][r] + bias_v[n];
                if (BF16_OUT) {
                    ((short*)Cout)[(size_t)rg * N + cg] = f2bf(v);
                } else {
                    if (RESID) v += resid[(size_t)rg * N + cg];
                    ((float*)Cout)[(size_t)rg * N + cg] = v;
                }
            }
        }
}

// ------------------------------------------------- V transpose: qkv bf16 -> Vt[b,h,d,t]
__global__ __launch_bounds__(256) void vt_kernel(const short* __restrict__ qkv,
                                                 short* __restrict__ Vt) {
    int bh = blockIdx.y;
    int b = bh >> 4, hh = bh & 15;
    int t0 = blockIdx.x * 64;
    __shared__ short tile[64 * 72];
    int tc = threadIdx.x & 7, tr = threadIdx.x >> 3;  // tr 0..31
    const short* src = qkv + (size_t)(b * T_SEQ + t0) * (3 * DM) + 2 * DM + hh * DH;
    for (int p = 0; p < 2; ++p) {
        int r = tr + p * 32;
        *(short8*)&tile[r * 72 + tc * 8] = *(const short8*)(src + (size_t)r * (3 * DM) + tc * 8);
    }
    __syncthreads();
    short* dst = Vt + (size_t)bh * DH * T_SEQ + t0;
    for (int p = 0; p < 2; ++p) {
        int d = tr + p * 32;
        short tmp[8];
#pragma unroll
        for (int j = 0; j < 8; ++j) tmp[j] = tile[(tc * 8 + j) * 72 + d];
        *(short8*)(dst + (size_t)d * T_SEQ + tc * 8) =
            short8{tmp[0], tmp[1], tmp[2], tmp[3], tmp[4], tmp[5], tmp[6], tmp[7]};
    }
}

// ------------------------------------------------------- MFMA flash attention (bf16 I/O)
// Block = 64 q-rows of one (b,h); 4 waves x 16 q-rows. K staged via global_load_lds
// with XOR-swizzled 16B chunks (conflict-free frag reads without padding).
// PV computed as O^T = Vt(A) @ P^T(B): both fragments are contiguous vector LDS reads.
__global__ __launch_bounds__(256) void attn_kernel(const short* __restrict__ qkv,
                                                   const short* __restrict__ Vt,
                                                   float* __restrict__ attn,
                                                   short* __restrict__ ao) {
    int blk = blockIdx.x;
    int qt = (T_SEQ / 64 - 1) - (blk & 31);  // big-q first
    int bh = blk >> 5;
    int b = bh >> 4, hh = bh & 15;
    int q0 = qt * 64;
    int tid = threadIdx.x;
    int wave = tid >> 6, lane = tid & 63;
    int l15 = lane & 15, quad = lane >> 4;

    __shared__ short Ks[64 * 64];      // [t][kchunk^(t&7)] swizzled
    __shared__ short Vs[64 * 64];      // Vt tile [d][tchunk^(d&7)] swizzled
    __shared__ short Ps[4 * 16 * 72];  // per-wave P [q][t], stride 72

    const float scale = 0.125f;
    const short* Qg = qkv + (size_t)(b * T_SEQ + q0) * (3 * DM) + hh * DH;
    const short* Kg = qkv + (size_t)(b * T_SEQ) * (3 * DM) + DM + hh * DH;
    const short* Vg = Vt + (size_t)bh * DH * T_SEQ;

    // Q fragments straight from global (one-time, 2x16B per lane)
    short8 qa[2];
    for (int d0 = 0; d0 < 2; ++d0)
        qa[d0] = *(const short8*)(Qg + (size_t)(wave * 16 + l15) * (3 * DM) + d0 * 32 + quad * 8);

    int ktiles = qt + 1;
    int qrow = q0 + wave * 16 + quad * 4;  // + r

    // ---- pass 1: softmax denominators
    float lsum[4] = {0.f, 0.f, 0.f, 0.f};
    for (int kt = 0; kt < ktiles; ++kt) {
        __syncthreads();
        for (int i = 0; i < 2; ++i) {
            int c = (wave * 2 + i) * 64 + lane;  // 512 chunks: row=c>>3, kc=c&7
            int row = c >> 3, kc = c & 7;
            int kcs = kc ^ (row & 7);
            gl2lds16(Kg + (size_t)(kt * 64 + row) * (3 * DM) + kcs * 8, &Ks[(wave * 2 + i) * 512]);
        }
        __syncthreads();
        floatx4 sacc[4] = {};
        for (int n0 = 0; n0 < 4; ++n0) {
            int row = n0 * 16 + l15;
            for (int d0 = 0; d0 < 2; ++d0) {
                int cc = (d0 * 4 + quad) ^ (row & 7);
                short8 kb = *(const short8*)&Ks[row * 64 + cc * 8];
                sacc[n0] = __builtin_amdgcn_mfma_f32_16x16x32_bf16(qa[d0], kb, sacc[n0], 0, 0, 0);
            }
        }
        int kbase = kt * 64 + l15;
        for (int r = 0; r < 4; ++r) {
            float s = 0.f;
            for (int n0 = 0; n0 < 4; ++n0)
                s += (kbase + n0 * 16 <= qrow + r) ? __expf(sacc[n0][r] * scale) : 0.f;
            s += __shfl_xor(s, 1); s += __shfl_xor(s, 2);
            s += __shfl_xor(s, 4); s += __shfl_xor(s, 8);
            lsum[r] += s;
        }
    }
    float invl[4];
    for (int r = 0; r < 4; ++r) invl[r] = 1.0f / lsum[r];

    // ---- pass 2
    floatx4 oacc[4] = {};  // O^T tiles: m0 -> d=m0*16+quad*4+r, n -> q=wave*16+l15
    float* abase = attn + (size_t)bh * T_SEQ * T_SEQ;
    for (int kt = 0; kt < T_SEQ / 64; ++kt) {
        if (kt < ktiles) {
            __syncthreads();
            for (int i = 0; i < 2; ++i) {
                int c = (wave * 2 + i) * 64 + lane;
                int row = c >> 3, kc = c & 7;
                int kcs = kc ^ (row & 7);
                gl2lds16(Kg + (size_t)(kt * 64 + row) * (3 * DM) + kcs * 8, &Ks[(wave * 2 + i) * 512]);
                gl2lds16(Vg + (size_t)row * T_SEQ + kt * 64 + kcs * 8, &Vs[(wave * 2 + i) * 512]);
            }
            __syncthreads();
            floatx4 sacc[4] = {};
            for (int n0 = 0; n0 < 4; ++n0) {
                int row = n0 * 16 + l15;
                for (int d0 = 0; d0 < 2; ++d0) {
                    int cc = (d0 * 4 + quad) ^ (row & 7);
                    short8 kb = *(const short8*)&Ks[row * 64 + cc * 8];
                    sacc[n0] = __builtin_amdgcn_mfma_f32_16x16x32_bf16(qa[d0], kb, sacc[n0], 0, 0, 0);
                }
            }
            int kbase = kt * 64 + l15;
            short* Pw = &Ps[wave * 1152];
            for (int n0 = 0; n0 < 4; ++n0)
                for (int r = 0; r < 4; ++r) {
                    float p = (kbase + n0 * 16 <= qrow + r)
                                  ? __expf(sacc[n0][r] * scale) * invl[r] : 0.f;
                    abase[(size_t)(qrow + r) * T_SEQ + kbase + n0 * 16] = p;
                    Pw[(quad * 4 + r) * 72 + n0 * 16 + l15] = f2bf(p);
                }
            __syncthreads();
            // O^T += Vt_tile(A) @ P^T(B)
            for (int m0 = 0; m0 < 4; ++m0) {
                int d = m0 * 16 + l15;
                for (int k0 = 0; k0 < 2; ++k0) {
                    int cc = (k0 * 4 + quad) ^ (d & 7);
                    short8 va = *(const short8*)&Vs[d * 64 + cc * 8];
                    short8 pb = ld8(&Pw[l15 * 72 + (k0 * 4 + quad) * 8]);
                    oacc[m0] = __builtin_amdgcn_mfma_f32_16x16x32_bf16(va, pb, oacc[m0], 0, 0, 0);
                }
            }
        } else {
            int kbase = kt * 64 + l15;
            for (int n0 = 0; n0 < 4; ++n0)
                for (int r = 0; r < 4; ++r)
                    abase[(size_t)(qrow + r) * T_SEQ + kbase + n0 * 16] = 0.f;
        }
    }
    // ---- epilogue: transpose O^T -> O rows via LDS, store bf16 coalesced
    short* Pw = &Ps[wave * 1152];
    __syncthreads();
    for (int m0 = 0; m0 < 4; ++m0)
        for (int r = 0; r < 4; ++r)
            Pw[l15 * 72 + m0 * 16 + quad * 4 + r] = f2bf(oacc[m0][r]);
    __syncthreads();
    for (int p = 0; p < 2; ++p) {
        int lq = (lane >> 3) + p * 8;
        int dc = lane & 7;
        short8 o8 = ld8(&Pw[lq * 72 + dc * 8]);
        *(short8*)(ao + (size_t)(b * T_SEQ + q0 + wave * 16 + lq) * DM + hh * DH + dc * 8) = o8;
    }
}

// ---------------------------------------------------------------- launch
extern "C" void kernel_launch(void* const* d_in, const int* in_sizes, int n_in,
                              void* d_out, int out_size, void* d_ws, size_t ws_size,
                              hipStream_t stream) {
    const float* x     = (const float*)d_in[0];
    const float* ln_g  = (const float*)d_in[1];
    const float* ln_b  = (const float*)d_in[2];
    const float* qkv_w = (const float*)d_in[3];
    const float* qkv_b = (const float*)d_in[4];
    const float* out_w = (const float*)d_in[5];
    const float* out_b = (const float*)d_in[6];

    float* xout = (float*)d_out;
    float* attn = xout + (size_t)ROWS * DM;

    short* h    = (short*)d_ws;                       // [4096,1024] bf16
    short* qkvT = h + (size_t)ROWS * DM;              // [3072,1024] bf16
    short* outT = qkvT + (size_t)(3 * DM) * DM;       // [1024,1024] bf16
    short* qkv  = outT + (size_t)DM * DM;             // [4096,3072] bf16
    short* Vt   = qkv + (size_t)ROWS * 3 * DM;        // [32,64,2048] bf16
    short* ao   = Vt + (size_t)B_SZ * NH * DH * T_SEQ;// [4096,1024] bf16

    ln_kernel<<<ROWS, 256, 0, stream>>>(x, ln_g, ln_b, h);
    wt_kernel<<<dim3(3 * DM / 32, DM / 32), 256, 0, stream>>>(qkv_w, qkvT, DM, 3 * DM);
    wt_kernel<<<dim3(DM / 32, DM / 32), 256, 0, stream>>>(out_w, outT, DM, DM);

    mfma_gemm<false, true><<<dim3(3 * DM / 128, ROWS / 128), 256, 0, stream>>>(
        h, qkvT, qkv_b, nullptr, qkv, ROWS, 3 * DM, DM);

    vt_kernel<<<dim3(T_SEQ / 64, B_SZ * NH), 256, 0, stream>>>(qkv, Vt);

    attn_kernel<<<B_SZ * NH * (T_SEQ / 64), 256, 0, stream>>>(qkv, Vt, attn, ao);

    mfma_gemm<true, false><<<dim3(DM / 128, ROWS / 128), 256, 0, stream>>>(
        ao, outT, out_b, x, xout, ROWS, DM, DM);
}